// Round 8
// baseline (89.211 us; speedup 1.0000x reference)
//
#include <hip/hip_runtime.h>
#include <hip/hip_bf16.h>

#define NB 8
#define NC 16
#define NH 256
#define NW 256
#define ALIVE_THRESH 0.1f
#define UPDATE_RATE 0.25f

typedef __attribute__((ext_vector_type(8))) short bf16x8;
typedef __attribute__((ext_vector_type(4))) float f32x4;
typedef unsigned short ushort_t;

#define MFMA16(a, b, c) __builtin_amdgcn_mfma_f32_16x16x32_bf16((a), (b), (c), 0, 0, 0)

static __device__ __forceinline__ unsigned short f2bf(float f) {
    __hip_bfloat16 h = __float2bfloat16(f);          // RNE
    return __builtin_bit_cast(unsigned short, h);
}
static __device__ __forceinline__ float bf2f(unsigned short b) {
    union { unsigned u; float f; } x; x.u = ((unsigned)b) << 16; return x.f;
}
static __device__ __forceinline__ unsigned pack2(float lo, float hi) {
    return (unsigned)f2bf(lo) | ((unsigned)f2bf(hi) << 16);
}
static __device__ __forceinline__ float bfbits(unsigned w, int hi) {
    return bf2f((unsigned short)(hi ? (w >> 16) : (w & 0xffffu)));
}

// swizzled byte offset into the [256 px][64 bf16] activation LDS buffer
static __device__ __forceinline__ int ybyte(int px, int g) {
    return px * 128 + ((g ^ (px & 7)) << 4);
}

// ---------------------------------------------------------------------------
// Pre-kernel: pack W1(+b1 as k=48 row), W2, W3 into MFMA A-fragment order.
// ---------------------------------------------------------------------------
__global__ void prep_weights(const float* __restrict__ w1, const float* __restrict__ b1,
                             const float* __restrict__ w2, const float* __restrict__ w3,
                             int4* __restrict__ wf)
{
    const int f = blockIdx.x, l = threadIdx.x;
    const int lq = l >> 4, ln = l & 15;
    union { unsigned short us[8]; int4 v; } u;
    if (f < 8) {
        const int mt = f >> 1, ks = f & 1, m = mt * 16 + ln;
        #pragma unroll
        for (int j = 0; j < 8; ++j) {
            const int k = ks * 32 + lq * 8 + j;
            float v = (k < 48) ? w1[m * 48 + k] : ((k == 48) ? b1[m] : 0.0f);
            u.us[j] = f2bf(v);
        }
    } else if (f < 16) {
        const int ff = f - 8, mt = ff >> 1, ks = ff & 1, m = mt * 16 + ln;
        #pragma unroll
        for (int j = 0; j < 8; ++j)
            u.us[j] = f2bf(w2[m * 64 + (ks * 32 + lq * 8 + j)]);
    } else {
        const int ks = f - 16, m = ln;
        #pragma unroll
        for (int j = 0; j < 8; ++j)
            u.us[j] = f2bf(w3[m * 64 + (ks * 32 + lq * 8 + j)]);
    }
    wf[f * 64 + l] = u.v;
}

// ---------------------------------------------------------------------------
// MLP GEMM body (unchanged, verified). Wave-private ybuf reads; no barriers.
// ---------------------------------------------------------------------------
template<typename ResF, typename OutF>
static __device__ __forceinline__ void mlp_gemm(
    char* yb, int lane, int px0,
    const int4* __restrict__ wf, const float* __restrict__ b2,
    const float* __restrict__ umr, ResF getres, OutF putout)
{
    const int lq = lane >> 4, ln = lane & 15;

    float umv[4];
    #pragma unroll
    for (int nt = 0; nt < 4; ++nt)
        umv[nt] = (umr[px0 + nt * 16 + ln] < UPDATE_RATE) ? 1.0f : 0.0f;

    bf16x8 a1f[8];
    #pragma unroll
    for (int f = 0; f < 8; ++f)
        a1f[f] = __builtin_bit_cast(bf16x8, wf[f * 64 + lane]);

    #pragma unroll
    for (int nt = 0; nt < 4; ++nt) {
        const int px = px0 + nt * 16 + ln;
        bf16x8 bb0 = *(const bf16x8*)(yb + ybyte(px, lq));
        bf16x8 bb1 = *(const bf16x8*)(yb + ybyte(px, 4 + lq));
        #pragma unroll
        for (int mt = 0; mt < 4; ++mt) {
            f32x4 z = {0.f, 0.f, 0.f, 0.f};
            z = MFMA16(a1f[2 * mt],     bb0, z);
            z = MFMA16(a1f[2 * mt + 1], bb1, z);
            union { unsigned w[2]; uint2 v; } pk;
            pk.w[0] = pack2(fmaxf(z[0], 0.f), fmaxf(z[1], 0.f));
            pk.w[1] = pack2(fmaxf(z[2], 0.f), fmaxf(z[3], 0.f));
            *(uint2*)(yb + ybyte(px, 2 * mt + (lq >> 1)) + (lq & 1) * 8) = pk.v;
        }
    }

    bf16x8 a2f[8];
    #pragma unroll
    for (int f = 0; f < 8; ++f)
        a2f[f] = __builtin_bit_cast(bf16x8, wf[(8 + f) * 64 + lane]);
    f32x4 b2v[4];
    #pragma unroll
    for (int mt = 0; mt < 4; ++mt)
        b2v[mt] = *(const f32x4*)(b2 + mt * 16 + lq * 4);

    #pragma unroll
    for (int nt = 0; nt < 4; ++nt) {
        const int px = px0 + nt * 16 + ln;
        bf16x8 bb0 = *(const bf16x8*)(yb + ybyte(px, lq));
        bf16x8 bb1 = *(const bf16x8*)(yb + ybyte(px, 4 + lq));
        #pragma unroll
        for (int mt = 0; mt < 4; ++mt) {
            f32x4 z = {0.f, 0.f, 0.f, 0.f};
            z = MFMA16(a2f[2 * mt],     bb0, z);
            z = MFMA16(a2f[2 * mt + 1], bb1, z);
            z = z + b2v[mt];
            union { unsigned w[2]; uint2 v; } pk;
            pk.w[0] = pack2(fmaxf(z[0], 0.f), fmaxf(z[1], 0.f));
            pk.w[1] = pack2(fmaxf(z[2], 0.f), fmaxf(z[3], 0.f));
            *(uint2*)(yb + ybyte(px, 2 * mt + (lq >> 1)) + (lq & 1) * 8) = pk.v;
        }
    }

    bf16x8 a3f0 = __builtin_bit_cast(bf16x8, wf[16 * 64 + lane]);
    bf16x8 a3f1 = __builtin_bit_cast(bf16x8, wf[17 * 64 + lane]);

    #pragma unroll
    for (int nt = 0; nt < 4; ++nt) {
        const int px = px0 + nt * 16 + ln;
        bf16x8 bb0 = *(const bf16x8*)(yb + ybyte(px, lq));
        bf16x8 bb1 = *(const bf16x8*)(yb + ybyte(px, 4 + lq));
        f32x4 z = {0.f, 0.f, 0.f, 0.f};
        z = MFMA16(a3f0, bb0, z);
        z = MFMA16(a3f1, bb1, z);
        f32x4 res = getres(px, lq, nt);
        #pragma unroll
        for (int r = 0; r < 4; ++r)
            putout(px, lq, r, res[r] + z[r] * umv[nt]);
    }
}

// ---------------------------------------------------------------------------
// shared y-combine + ybuf fill from per-lane packed (s|d) + halo (s|d).
// Lane t handles col t; L/R neighbors via shuffles; boundary lanes use sdH.
// ---------------------------------------------------------------------------
static __device__ __forceinline__ void combine_store_y(
    char* yb, int t, int lane,
    const unsigned* sdreg, const unsigned* sdH,
    const float* mreg, const float* dreg)
{
    unsigned yp[24];
    {
        unsigned short ys[48];
        #pragma unroll
        for (int c = 0; c < NC; ++c) {
            unsigned Lw = __shfl_up(sdreg[c], 1);
            unsigned Rw = __shfl_down(sdreg[c], 1);
            if (lane == 0)  Lw = sdH[c];
            if (lane == 63) Rw = sdH[c];
            float sl = bfbits(Lw, 0), dl = bfbits(Lw, 1);
            float sr = bfbits(Rw, 0), dr = bfbits(Rw, 1);
            ys[3 * c + 0] = f2bf(mreg[c]);
            ys[3 * c + 1] = f2bf(sr - sl);
            ys[3 * c + 2] = f2bf(dl + 2.0f * dreg[c] + dr);
        }
        #pragma unroll
        for (int i = 0; i < 24; ++i)
            yp[i] = (unsigned)ys[2 * i] | ((unsigned)ys[2 * i + 1] << 16);
    }
    #pragma unroll
    for (int g = 0; g < 6; ++g) {
        union { unsigned w[4]; int4 v; } pk;
        pk.w[0] = yp[4 * g]; pk.w[1] = yp[4 * g + 1];
        pk.w[2] = yp[4 * g + 2]; pk.w[3] = yp[4 * g + 3];
        *(int4*)(yb + ybyte(t, g)) = pk.v;
    }
    { int4 br; br.x = 0x3F80; br.y = 0; br.z = 0; br.w = 0;
      *(int4*)(yb + ybyte(t, 6)) = br; }               // k=48 -> 1.0 (bias)
    { int4 zz; zz.x = zz.y = zz.z = zz.w = 0;
      *(int4*)(yb + ybyte(t, 7)) = zz; }
}

// ---------------------------------------------------------------------------
// First step: f32 planar input -> bf16 planar unmasked state + pre mask.
// ZERO barriers.
// ---------------------------------------------------------------------------
__global__ __launch_bounds__(256) void nca_first(
    const float* __restrict__ x,
    const float* __restrict__ um,
    const int4*  __restrict__ wf,
    const float* __restrict__ b2,
    ushort_t* __restrict__ xout,
    unsigned char* __restrict__ preb_out)
{
    __shared__ char smem[256 * 128];          // ybuf only, 32 KB
    char* yb = smem;

    const int t = threadIdx.x, bx = blockIdx.x;
    const int h = ((bx & 7) << 5) | (bx >> 3);       // XCD-chunked row swizzle
    const int b = blockIdx.y;
    const int hm = (h - 1) & 255, hp = (h + 1) & 255;
    const size_t cs = (size_t)NH * NW;
    const size_t base = (size_t)b * NC * cs;
    const int lane = t & 63;

    // ---- pre-alive: own 3x3 f32 alpha window -------------------------------
    {
        const float* a3p = x + base + 3 * cs;
        float mx = -1e30f;
        #pragma unroll
        for (int r = 0; r < 3; ++r) {
            const float* rp = a3p + (size_t)((h - 1 + r) & 255) * NW;
            #pragma unroll
            for (int d = 0; d < 3; ++d)
                mx = fmaxf(mx, rp[(t - 1 + d) & 255]);
        }
        preb_out[((size_t)b * NH + h) * NW + t] = (mx > ALIVE_THRESH) ? 1 : 0;
    }

    // ---- per-lane vertical smooth/diff (own col) + halo col ----------------
    const bool isHalo = (lane == 0) || (lane == 63);
    const int hc = (lane == 0) ? ((t - 1) & 255) : ((t + 1) & 255);

    unsigned sdreg[NC], sdH[NC];
    float mreg[NC], dreg[NC];
    #pragma unroll
    for (int c = 0; c < NC; ++c) {
        const float* xc = x + base + (size_t)c * cs;
        float top = xc[(size_t)hm * NW + t];
        float mid = xc[(size_t)h  * NW + t];
        float bot = xc[(size_t)hp * NW + t];
        sdreg[c] = pack2(top + 2.0f * mid + bot, bot - top);
        mreg[c] = mid; dreg[c] = bot - top;

        float ht = 0.f, hmid = 0.f, hb = 0.f;
        if (isHalo) {
            ht   = xc[(size_t)hm * NW + hc];
            hmid = xc[(size_t)h  * NW + hc];
            hb   = xc[(size_t)hp * NW + hc];
        }
        sdH[c] = pack2(ht + 2.0f * hmid + hb, hb - ht);
    }

    combine_store_y(yb, t, lane, sdreg, sdH, mreg, dreg);

    const int wv = t >> 6;
    const float* umr = um + ((size_t)b * NH + h) * NW;

    auto getres = [&](int px, int lq, int) -> f32x4 {
        f32x4 r;
        #pragma unroll
        for (int i = 0; i < 4; ++i)
            r[i] = x[base + (size_t)(lq * 4 + i) * cs + (size_t)h * NW + px];
        return r;
    };
    auto putout = [&](int px, int lq, int r, float v) {
        xout[base + (size_t)(lq * 4 + r) * cs + (size_t)h * NW + px] = f2bf(v);
    };
    mlp_gemm(yb, lane, wv * 64, wf, b2, umr, getres, putout);
}

// ---------------------------------------------------------------------------
// Later steps: bf16 planar unmasked state + prev pre mask in; pre*post masks
// in registers (5x5 window). ZERO barriers.
// ---------------------------------------------------------------------------
__global__ __launch_bounds__(256) void nca_step(
    const ushort_t* __restrict__ xin,
    const unsigned char* __restrict__ preb_in,
    const float* __restrict__ um,
    const int4*  __restrict__ wf,
    const float* __restrict__ b2,
    ushort_t* __restrict__ xout,
    unsigned char* __restrict__ preb_out)
{
    __shared__ char smem[256 * 128];          // ybuf only, 32 KB
    char* yb = smem;

    const int t = threadIdx.x, bx = blockIdx.x;
    const int h = ((bx & 7) << 5) | (bx >> 3);
    const int b = blockIdx.y;
    const int hm = (h - 1) & 255, hp = (h + 1) & 255;
    const size_t cs = (size_t)NH * NW;
    const size_t base = (size_t)b * NC * cs;
    const size_t prow = (size_t)b * NH;
    const int lane = t & 63;

    // ---- 5x5 alpha window (planar, coalesced) ------------------------------
    float a[5][5];
    {
        const ushort_t* a3p = xin + base + 3 * cs;
        #pragma unroll
        for (int j = 0; j < 5; ++j) {
            const ushort_t* rp = a3p + (size_t)((h - 2 + j) & 255) * NW;
            #pragma unroll
            for (int d = 0; d < 5; ++d)
                a[j][d] = bf2f(rp[(t - 2 + d) & 255]);
        }
    }

    // ---- post(prev) & combined masks for rows h-1..h+1, cols t-1..t+1 ------
    float m3x3[3][3];
    #pragma unroll
    for (int r = 0; r < 3; ++r) {
        float cm[5];
        #pragma unroll
        for (int d = 0; d < 5; ++d)
            cm[d] = fmaxf(fmaxf(a[r][d], a[r + 1][d]), a[r + 2][d]);
        #pragma unroll
        for (int dd = 0; dd < 3; ++dd) {
            float post = fmaxf(fmaxf(cm[dd], cm[dd + 1]), cm[dd + 2]);
            const int hh = (h - 1 + r) & 255, uu = (t - 1 + dd) & 255;
            unsigned char p = preb_in[(prow + hh) * NW + uu];
            m3x3[r][dd] = (post > ALIVE_THRESH && p) ? 1.0f : 0.0f;
        }
    }

    // ---- pre mask of THIS step ---------------------------------------------
    {
        float pm = 0.0f;
        #pragma unroll
        for (int r = 0; r < 3; ++r)
            #pragma unroll
            for (int dd = 0; dd < 3; ++dd)
                pm = fmaxf(pm, a[1 + r][1 + dd] * m3x3[r][dd]);
        preb_out[(prow + h) * NW + t] = (pm > ALIVE_THRESH) ? 1 : 0;
    }

    const float m0 = m3x3[0][1], m1 = m3x3[1][1], m2 = m3x3[2][1];

    // ---- per-lane masked smooth/diff (own col) + halo col ------------------
    // Halo masks already live in boundary lanes' m3x3 column 0 / column 2.
    const bool isHalo = (lane == 0) || (lane == 63);
    const int hc = (lane == 0) ? ((t - 1) & 255) : ((t + 1) & 255);
    const int hd = (lane == 0) ? 1 : 3;          // halo col in a[][] d-index
    const float hk0 = (lane == 0) ? m3x3[0][0] : m3x3[0][2];
    const float hk1 = (lane == 0) ? m3x3[1][0] : m3x3[1][2];
    const float hk2 = (lane == 0) ? m3x3[2][0] : m3x3[2][2];

    unsigned sdreg[NC], sdH[NC];
    float mreg[NC], dreg[NC];
    #pragma unroll
    for (int c = 0; c < NC; ++c) {
        float top, mid, bot, ht, hmid, hb;
        if (c == 3) {
            top = a[1][2] * m0; mid = a[2][2] * m1; bot = a[3][2] * m2;
            ht = a[1][hd] * hk0; hmid = a[2][hd] * hk1; hb = a[3][hd] * hk2;
        } else {
            const ushort_t* xc = xin + base + (size_t)c * cs;
            top = bf2f(xc[(size_t)hm * NW + t]) * m0;
            mid = bf2f(xc[(size_t)h  * NW + t]) * m1;
            bot = bf2f(xc[(size_t)hp * NW + t]) * m2;
            ht = 0.f; hmid = 0.f; hb = 0.f;
            if (isHalo) {
                ht   = bf2f(xc[(size_t)hm * NW + hc]) * hk0;
                hmid = bf2f(xc[(size_t)h  * NW + hc]) * hk1;
                hb   = bf2f(xc[(size_t)hp * NW + hc]) * hk2;
            }
        }
        sdreg[c] = pack2(top + 2.0f * mid + bot, bot - top);
        mreg[c] = mid; dreg[c] = bot - top;
        sdH[c] = pack2(ht + 2.0f * hmid + hb, hb - ht);
    }

    combine_store_y(yb, t, lane, sdreg, sdH, mreg, dreg);

    const int wv = t >> 6;
    const float* umr = um + (prow + h) * NW;

    auto getres = [&](int px, int lq, int) -> f32x4 {
        const float mm = __shfl(m1, px & 63);
        f32x4 r;
        #pragma unroll
        for (int i = 0; i < 4; ++i)
            r[i] = bf2f(xin[base + (size_t)(lq * 4 + i) * cs + (size_t)h * NW + px]) * mm;
        return r;
    };
    auto putout = [&](int px, int lq, int r, float v) {
        xout[base + (size_t)(lq * 4 + r) * cs + (size_t)h * NW + px] = f2bf(v);
    };
    mlp_gemm(yb, lane, wv * 64, wf, b2, umr, getres, putout);
}

// ---------------------------------------------------------------------------
// Final: post-alive on bf16 planar state, apply pre*post, f32 planar out.
// ---------------------------------------------------------------------------
__global__ __launch_bounds__(256) void nca_final(
    const ushort_t* __restrict__ xin,
    const unsigned char* __restrict__ preb,
    float* __restrict__ xout)
{
    const int t = threadIdx.x, bx = blockIdx.x;
    const int h = ((bx & 7) << 5) | (bx >> 3);
    const int b = blockIdx.y;
    const size_t cs = (size_t)NH * NW;
    const size_t base = (size_t)b * NC * cs;

    const ushort_t* a3p = xin + base + 3 * cs;
    float mx = -1e30f;
    #pragma unroll
    for (int r = 0; r < 3; ++r) {
        const ushort_t* rp = a3p + (size_t)((h - 1 + r) & 255) * NW;
        #pragma unroll
        for (int d = 0; d < 3; ++d)
            mx = fmaxf(mx, bf2f(rp[(t - 1 + d) & 255]));
    }
    const float m = (mx > ALIVE_THRESH && preb[((size_t)b * NH + h) * NW + t])
                        ? 1.0f : 0.0f;

    const size_t off = (size_t)h * NW + t;
    #pragma unroll
    for (int c = 0; c < NC; ++c)
        xout[base + (size_t)c * cs + off] = bf2f(xin[base + (size_t)c * cs + off]) * m;
}

// ---------------------------------------------------------------------------
extern "C" void kernel_launch(void* const* d_in, const int* in_sizes, int n_in,
                              void* d_out, int out_size, void* d_ws, size_t ws_size,
                              hipStream_t stream) {
    const float* x  = (const float*)d_in[0];
    const float* w1 = (const float*)d_in[1];
    const float* b1 = (const float*)d_in[2];
    const float* w2 = (const float*)d_in[3];
    const float* b2 = (const float*)d_in[4];
    const float* w3 = (const float*)d_in[5];
    const float* um = (const float*)d_in[6];
    const int steps = in_sizes[6] / (NB * NH * NW);

    const size_t npix  = (size_t)NB * NH * NW;
    const size_t nelem = (size_t)NB * NC * NH * NW;

    ushort_t* bfA        = (ushort_t*)d_ws;                 // 16 MB
    ushort_t* bfB        = bfA + nelem;                     // 16 MB
    unsigned char* prebA = (unsigned char*)(bfB + nelem);   // 512 KB
    unsigned char* prebB = prebA + npix;                    // 512 KB
    int4* wf             = (int4*)(prebB + npix);           // 18 KB
    float* xout          = (float*)d_out;

    prep_weights<<<18, 64, 0, stream>>>(w1, b1, w2, w3, wf);

    dim3 grd(NH, NB);

    const ushort_t* cur = bfA;
    unsigned char* preb_last = prebA;

    for (int i = 0; i < steps; ++i) {
        const float* um_i = um + (size_t)i * npix;
        ushort_t* bfo      = (i % 2 == 0) ? bfA : bfB;
        unsigned char* po  = (i % 2 == 0) ? prebA : prebB;
        unsigned char* pin = (i % 2 == 0) ? prebB : prebA;

        if (i == 0)
            nca_first<<<grd, 256, 0, stream>>>(x, um_i, wf, b2, bfo, po);
        else
            nca_step<<<grd, 256, 0, stream>>>(cur, pin, um_i, wf, b2, bfo, po);
        cur = bfo;
        preb_last = po;
    }

    nca_final<<<grd, 256, 0, stream>>>(cur, preb_last, xout);
}

// Round 9
// 76.753 us; speedup vs baseline: 1.1623x; 1.1623x over previous
//
#include <hip/hip_runtime.h>
#include <hip/hip_bf16.h>

#define NB 8
#define NC 16
#define NH 256
#define NW 256
#define ALIVE_THRESH 0.1f
#define UPDATE_RATE 0.25f

typedef __attribute__((ext_vector_type(8))) short bf16x8;
typedef __attribute__((ext_vector_type(4))) float f32x4;
typedef unsigned short ushort_t;

#define MFMA16(a, b, c) __builtin_amdgcn_mfma_f32_16x16x32_bf16((a), (b), (c), 0, 0, 0)

static __device__ __forceinline__ unsigned short f2bf(float f) {
    __hip_bfloat16 h = __float2bfloat16(f);          // RNE
    return __builtin_bit_cast(unsigned short, h);
}
static __device__ __forceinline__ float bf2f(unsigned short b) {
    union { unsigned u; float f; } x; x.u = ((unsigned)b) << 16; return x.f;
}
static __device__ __forceinline__ unsigned pack2(float lo, float hi) {
    return (unsigned)f2bf(lo) | ((unsigned)f2bf(hi) << 16);
}
static __device__ __forceinline__ float bfbits(unsigned w, int hi) {
    return bf2f((unsigned short)(hi ? (w >> 16) : (w & 0xffffu)));
}

// compile-time word selector from two uint4s — pure member access, never
// takes an address (r5 lesson: pointer-cast of vector regs -> scratch).
#define W16(q0, q1, i) ((i) == 0 ? (q0).x : (i) == 1 ? (q0).y : (i) == 2 ? (q0).z : \
                        (i) == 3 ? (q0).w : (i) == 4 ? (q1).x : (i) == 5 ? (q1).y : \
                        (i) == 6 ? (q1).z : (q1).w)

// swizzled byte offset into the [256 px][64 bf16] activation LDS buffer
static __device__ __forceinline__ int ybyte(int px, int g) {
    return px * 128 + ((g ^ (px & 7)) << 4);
}

// ---------------------------------------------------------------------------
// Pre-kernel: pack W1(+b1 as k=48 row), W2, W3 into MFMA A-fragment order.
// ---------------------------------------------------------------------------
__global__ void prep_weights(const float* __restrict__ w1, const float* __restrict__ b1,
                             const float* __restrict__ w2, const float* __restrict__ w3,
                             int4* __restrict__ wf)
{
    const int f = blockIdx.x, l = threadIdx.x;
    const int lq = l >> 4, ln = l & 15;
    union { unsigned short us[8]; int4 v; } u;
    if (f < 8) {
        const int mt = f >> 1, ks = f & 1, m = mt * 16 + ln;
        #pragma unroll
        for (int j = 0; j < 8; ++j) {
            const int k = ks * 32 + lq * 8 + j;
            float v = (k < 48) ? w1[m * 48 + k] : ((k == 48) ? b1[m] : 0.0f);
            u.us[j] = f2bf(v);
        }
    } else if (f < 16) {
        const int ff = f - 8, mt = ff >> 1, ks = ff & 1, m = mt * 16 + ln;
        #pragma unroll
        for (int j = 0; j < 8; ++j)
            u.us[j] = f2bf(w2[m * 64 + (ks * 32 + lq * 8 + j)]);
    } else {
        const int ks = f - 16, m = ln;
        #pragma unroll
        for (int j = 0; j < 8; ++j)
            u.us[j] = f2bf(w3[m * 64 + (ks * 32 + lq * 8 + j)]);
    }
    wf[f * 64 + l] = u.v;
}

// ---------------------------------------------------------------------------
// combine (horizontal sobel from sd LDS) + ybuf fill. Contains both barriers.
// Caller must have written sd[c*NW + t] for all t before calling.
// ---------------------------------------------------------------------------
static __device__ __forceinline__ void combine_store(
    char* yb, unsigned* sd, int t, const float* mreg, const float* dreg)
{
    __syncthreads();                                  // B1: sd ready
    const int tm = (t - 1) & 255, tp = (t + 1) & 255;
    unsigned yp[24];
    {
        unsigned short ys[48];
        #pragma unroll
        for (int c = 0; c < NC; ++c) {
            unsigned L = sd[c * NW + tm], R = sd[c * NW + tp];
            float sl = bfbits(L, 0), dl = bfbits(L, 1);
            float sr = bfbits(R, 0), dr = bfbits(R, 1);
            ys[3 * c + 0] = f2bf(mreg[c]);
            ys[3 * c + 1] = f2bf(sr - sl);
            ys[3 * c + 2] = f2bf(dl + 2.0f * dreg[c] + dr);
        }
        #pragma unroll
        for (int i = 0; i < 24; ++i)
            yp[i] = (unsigned)ys[2 * i] | ((unsigned)ys[2 * i + 1] << 16);
    }
    __syncthreads();                                  // B2: sd dead, ybuf safe

    #pragma unroll
    for (int g = 0; g < 6; ++g) {
        union { unsigned w[4]; int4 v; } pk;
        pk.w[0] = yp[4 * g]; pk.w[1] = yp[4 * g + 1];
        pk.w[2] = yp[4 * g + 2]; pk.w[3] = yp[4 * g + 3];
        *(int4*)(yb + ybyte(t, g)) = pk.v;
    }
    { int4 br; br.x = 0x3F80; br.y = 0; br.z = 0; br.w = 0;
      *(int4*)(yb + ybyte(t, 6)) = br; }              // k=48 -> 1.0 (bias)
    { int4 zz; zz.x = zz.y = zz.z = zz.w = 0;
      *(int4*)(yb + ybyte(t, 7)) = zz; }
}

// ---------------------------------------------------------------------------
// MLP GEMM body. putout(px, lq, f32x4) stores 4 channels at once.
// ---------------------------------------------------------------------------
template<typename ResF, typename OutF>
static __device__ __forceinline__ void mlp_gemm(
    char* yb, int lane, int px0,
    const int4* __restrict__ wf, const float* __restrict__ b2,
    const float* __restrict__ umr, ResF getres, OutF putout)
{
    const int lq = lane >> 4, ln = lane & 15;

    float umv[4];
    #pragma unroll
    for (int nt = 0; nt < 4; ++nt)
        umv[nt] = (umr[px0 + nt * 16 + ln] < UPDATE_RATE) ? 1.0f : 0.0f;

    bf16x8 a1f[8];
    #pragma unroll
    for (int f = 0; f < 8; ++f)
        a1f[f] = __builtin_bit_cast(bf16x8, wf[f * 64 + lane]);

    #pragma unroll
    for (int nt = 0; nt < 4; ++nt) {
        const int px = px0 + nt * 16 + ln;
        bf16x8 bb0 = *(const bf16x8*)(yb + ybyte(px, lq));
        bf16x8 bb1 = *(const bf16x8*)(yb + ybyte(px, 4 + lq));
        #pragma unroll
        for (int mt = 0; mt < 4; ++mt) {
            f32x4 z = {0.f, 0.f, 0.f, 0.f};
            z = MFMA16(a1f[2 * mt],     bb0, z);
            z = MFMA16(a1f[2 * mt + 1], bb1, z);
            union { unsigned w[2]; uint2 v; } pk;
            pk.w[0] = pack2(fmaxf(z[0], 0.f), fmaxf(z[1], 0.f));
            pk.w[1] = pack2(fmaxf(z[2], 0.f), fmaxf(z[3], 0.f));
            *(uint2*)(yb + ybyte(px, 2 * mt + (lq >> 1)) + (lq & 1) * 8) = pk.v;
        }
    }

    bf16x8 a2f[8];
    #pragma unroll
    for (int f = 0; f < 8; ++f)
        a2f[f] = __builtin_bit_cast(bf16x8, wf[(8 + f) * 64 + lane]);
    f32x4 b2v[4];
    #pragma unroll
    for (int mt = 0; mt < 4; ++mt)
        b2v[mt] = *(const f32x4*)(b2 + mt * 16 + lq * 4);

    #pragma unroll
    for (int nt = 0; nt < 4; ++nt) {
        const int px = px0 + nt * 16 + ln;
        bf16x8 bb0 = *(const bf16x8*)(yb + ybyte(px, lq));
        bf16x8 bb1 = *(const bf16x8*)(yb + ybyte(px, 4 + lq));
        #pragma unroll
        for (int mt = 0; mt < 4; ++mt) {
            f32x4 z = {0.f, 0.f, 0.f, 0.f};
            z = MFMA16(a2f[2 * mt],     bb0, z);
            z = MFMA16(a2f[2 * mt + 1], bb1, z);
            z = z + b2v[mt];
            union { unsigned w[2]; uint2 v; } pk;
            pk.w[0] = pack2(fmaxf(z[0], 0.f), fmaxf(z[1], 0.f));
            pk.w[1] = pack2(fmaxf(z[2], 0.f), fmaxf(z[3], 0.f));
            *(uint2*)(yb + ybyte(px, 2 * mt + (lq >> 1)) + (lq & 1) * 8) = pk.v;
        }
    }

    bf16x8 a3f0 = __builtin_bit_cast(bf16x8, wf[16 * 64 + lane]);
    bf16x8 a3f1 = __builtin_bit_cast(bf16x8, wf[17 * 64 + lane]);

    #pragma unroll
    for (int nt = 0; nt < 4; ++nt) {
        const int px = px0 + nt * 16 + ln;
        bf16x8 bb0 = *(const bf16x8*)(yb + ybyte(px, lq));
        bf16x8 bb1 = *(const bf16x8*)(yb + ybyte(px, 4 + lq));
        f32x4 z = {0.f, 0.f, 0.f, 0.f};
        z = MFMA16(a3f0, bb0, z);
        z = MFMA16(a3f1, bb1, z);
        f32x4 res = getres(px, lq, nt);
        f32x4 out;
        #pragma unroll
        for (int r = 0; r < 4; ++r)
            out[r] = res[r] + z[r] * umv[nt];
        putout(px, lq, out);
    }
}

// ---------------------------------------------------------------------------
// First step: f32 planar input -> channel-last bf16 state + alpha sidecar +
// pre mask. Output state lives in d_out's first 16 MB (dead before final).
// ---------------------------------------------------------------------------
__global__ __launch_bounds__(256, 4) void nca_first(
    const float* __restrict__ x,
    const float* __restrict__ um,
    const int4*  __restrict__ wf,
    const float* __restrict__ b2,
    ushort_t* __restrict__ ps_out,        // [B*H*W*16] channel-last
    ushort_t* __restrict__ sc_out,        // [B*H*W] unmasked alpha
    unsigned char* __restrict__ preb_out)
{
    __shared__ char smem[256 * 128];          // 32 KB; sd overlays first 16 KB
    char*     yb = smem;
    unsigned* sd = (unsigned*)smem;

    const int t = threadIdx.x, bx = blockIdx.x;
    const int h = ((bx & 7) << 5) | (bx >> 3);       // XCD-chunked row swizzle
    const int b = blockIdx.y;
    const int hm = (h - 1) & 255, hp = (h + 1) & 255;
    const size_t cs = (size_t)NH * NW;
    const size_t base = (size_t)b * NC * cs;
    const size_t prow = (size_t)b * NH;

    // ---- pre-alive: 3x3 f32 alpha window -----------------------------------
    {
        const float* a3p = x + base + 3 * cs;
        float mx = -1e30f;
        #pragma unroll
        for (int r = 0; r < 3; ++r) {
            const float* rp = a3p + (size_t)((h - 1 + r) & 255) * NW;
            #pragma unroll
            for (int d = 0; d < 3; ++d)
                mx = fmaxf(mx, rp[(t - 1 + d) & 255]);
        }
        preb_out[(prow + h) * NW + t] = (mx > ALIVE_THRESH) ? 1 : 0;
    }

    // ---- vertical smooth/diff -> sd ----------------------------------------
    float mreg[NC], dreg[NC];
    #pragma unroll
    for (int c = 0; c < NC; ++c) {
        const float* xc = x + base + (size_t)c * cs;
        float top = xc[(size_t)hm * NW + t];
        float mid = xc[(size_t)h  * NW + t];
        float bot = xc[(size_t)hp * NW + t];
        sd[c * NW + t] = pack2(top + 2.0f * mid + bot, bot - top);
        mreg[c] = mid; dreg[c] = bot - top;
    }

    combine_store(yb, sd, t, mreg, dreg);

    const int lane = t & 63, wv = t >> 6;
    const float* umr = um + (prow + h) * NW;

    auto getres = [&](int px, int lq, int) -> f32x4 {
        f32x4 r;
        #pragma unroll
        for (int i = 0; i < 4; ++i)
            r[i] = x[base + (size_t)(lq * 4 + i) * cs + (size_t)h * NW + px];
        return r;
    };
    auto putout = [&](int px, int lq, f32x4 v) {
        unsigned lo = pack2(v[0], v[1]);
        unsigned hi = pack2(v[2], v[3]);
        uint2 u; u.x = lo; u.y = hi;
        *(uint2*)(ps_out + ((prow + h) * NW + px) * 16 + lq * 4) = u;
        if (lq == 0)                                  // channel 3 = v[3]
            sc_out[(prow + h) * NW + px] = (ushort_t)(hi >> 16);
    };
    mlp_gemm(yb, lane, wv * 64, wf, b2, umr, getres, putout);
}

// ---------------------------------------------------------------------------
// Later steps: channel-last bf16 state + alpha sidecar + prev pre mask in;
// masks in registers (5x5 sidecar window); 6 vector loads for all 48 state
// values (vs 48 scalar).
// ---------------------------------------------------------------------------
__global__ __launch_bounds__(256, 4) void nca_step(
    const ushort_t* __restrict__ ps_in,
    const ushort_t* __restrict__ sc_in,
    const unsigned char* __restrict__ preb_in,
    const float* __restrict__ um,
    const int4*  __restrict__ wf,
    const float* __restrict__ b2,
    ushort_t* __restrict__ ps_out,
    ushort_t* __restrict__ sc_out,
    unsigned char* __restrict__ preb_out)
{
    __shared__ char smem[256 * 128];
    char*     yb = smem;
    unsigned* sd = (unsigned*)smem;

    const int t = threadIdx.x, bx = blockIdx.x;
    const int h = ((bx & 7) << 5) | (bx >> 3);
    const int b = blockIdx.y;
    const int hm = (h - 1) & 255, hp = (h + 1) & 255;
    const size_t prow = (size_t)b * NH;

    // ---- 5x5 alpha window from sidecar (planar, coalesced) -----------------
    float a[5][5];
    {
        #pragma unroll
        for (int j = 0; j < 5; ++j) {
            const ushort_t* rp = sc_in + (prow + ((h - 2 + j) & 255)) * NW;
            #pragma unroll
            for (int d = 0; d < 5; ++d)
                a[j][d] = bf2f(rp[(t - 2 + d) & 255]);
        }
    }

    // ---- post(prev) & combined masks, rows h-1..h+1 x cols t-1..t+1 --------
    float m3x3[3][3];
    #pragma unroll
    for (int r = 0; r < 3; ++r) {
        float cm[5];
        #pragma unroll
        for (int d = 0; d < 5; ++d)
            cm[d] = fmaxf(fmaxf(a[r][d], a[r + 1][d]), a[r + 2][d]);
        #pragma unroll
        for (int dd = 0; dd < 3; ++dd) {
            float post = fmaxf(fmaxf(cm[dd], cm[dd + 1]), cm[dd + 2]);
            const int hh = (h - 1 + r) & 255, uu = (t - 1 + dd) & 255;
            unsigned char p = preb_in[(prow + hh) * NW + uu];
            m3x3[r][dd] = (post > ALIVE_THRESH && p) ? 1.0f : 0.0f;
        }
    }

    // ---- pre mask of THIS step ---------------------------------------------
    {
        float pm = 0.0f;
        #pragma unroll
        for (int r = 0; r < 3; ++r)
            #pragma unroll
            for (int dd = 0; dd < 3; ++dd)
                pm = fmaxf(pm, a[1 + r][1 + dd] * m3x3[r][dd]);
        preb_out[(prow + h) * NW + t] = (pm > ALIVE_THRESH) ? 1 : 0;
    }

    const float m0 = m3x3[0][1], m1 = m3x3[1][1], m2 = m3x3[2][1];

    // ---- state: 3 rows channel-last, 2x uint4 each (6 vector loads) --------
    const uint4* pm4 = (const uint4*)(ps_in + ((prow + hm) * NW + t) * 16);
    const uint4* pc4 = (const uint4*)(ps_in + ((prow + h ) * NW + t) * 16);
    const uint4* pp4 = (const uint4*)(ps_in + ((prow + hp) * NW + t) * 16);
    uint4 qa0 = pm4[0], qa1 = pm4[1];
    uint4 qb0 = pc4[0], qb1 = pc4[1];
    uint4 qc0 = pp4[0], qc1 = pp4[1];

    float mreg[NC], dreg[NC];
    #pragma unroll
    for (int c = 0; c < NC; ++c) {
        float top = bfbits(W16(qa0, qa1, c >> 1), c & 1) * m0;
        float mid = bfbits(W16(qb0, qb1, c >> 1), c & 1) * m1;
        float bot = bfbits(W16(qc0, qc1, c >> 1), c & 1) * m2;
        sd[c * NW + t] = pack2(top + 2.0f * mid + bot, bot - top);
        mreg[c] = mid; dreg[c] = bot - top;
    }

    combine_store(yb, sd, t, mreg, dreg);

    const int lane = t & 63, wv = t >> 6;
    const float* umr = um + (prow + h) * NW;

    auto getres = [&](int px, int lq, int) -> f32x4 {
        const float mm = __shfl(m1, px & 63);         // owner lane in same wave
        uint2 v = *(const uint2*)(ps_in + ((prow + h) * NW + px) * 16 + lq * 4);
        f32x4 r;
        r[0] = bfbits(v.x, 0) * mm; r[1] = bfbits(v.x, 1) * mm;
        r[2] = bfbits(v.y, 0) * mm; r[3] = bfbits(v.y, 1) * mm;
        return r;
    };
    auto putout = [&](int px, int lq, f32x4 v) {
        unsigned lo = pack2(v[0], v[1]);
        unsigned hi = pack2(v[2], v[3]);
        uint2 u; u.x = lo; u.y = hi;
        *(uint2*)(ps_out + ((prow + h) * NW + px) * 16 + lq * 4) = u;
        if (lq == 0)
            sc_out[(prow + h) * NW + px] = (ushort_t)(hi >> 16);
    };
    mlp_gemm(yb, lane, wv * 64, wf, b2, umr, getres, putout);
}

// ---------------------------------------------------------------------------
// Final: post-alive from sidecar, apply pre*post, f32 planar out.
// ---------------------------------------------------------------------------
__global__ __launch_bounds__(256) void nca_final(
    const ushort_t* __restrict__ ps_in,
    const ushort_t* __restrict__ sc_in,
    const unsigned char* __restrict__ preb,
    float* __restrict__ xout)
{
    const int t = threadIdx.x, bx = blockIdx.x;
    const int h = ((bx & 7) << 5) | (bx >> 3);
    const int b = blockIdx.y;
    const size_t cs = (size_t)NH * NW;
    const size_t base = (size_t)b * NC * cs;
    const size_t prow = (size_t)b * NH;

    float mx = -1e30f;
    #pragma unroll
    for (int r = 0; r < 3; ++r) {
        const ushort_t* rp = sc_in + (prow + ((h - 1 + r) & 255)) * NW;
        #pragma unroll
        for (int d = 0; d < 3; ++d)
            mx = fmaxf(mx, bf2f(rp[(t - 1 + d) & 255]));
    }
    const float m = (mx > ALIVE_THRESH && preb[(prow + h) * NW + t]) ? 1.0f : 0.0f;

    const uint4* p4 = (const uint4*)(ps_in + ((prow + h) * NW + t) * 16);
    uint4 q0 = p4[0], q1 = p4[1];

    const size_t off = (size_t)h * NW + t;
    #pragma unroll
    for (int c = 0; c < NC; ++c)
        xout[base + (size_t)c * cs + off] = bfbits(W16(q0, q1, c >> 1), c & 1) * m;
}

// ---------------------------------------------------------------------------
extern "C" void kernel_launch(void* const* d_in, const int* in_sizes, int n_in,
                              void* d_out, int out_size, void* d_ws, size_t ws_size,
                              hipStream_t stream) {
    const float* x  = (const float*)d_in[0];
    const float* w1 = (const float*)d_in[1];
    const float* b1 = (const float*)d_in[2];
    const float* w2 = (const float*)d_in[3];
    const float* b2 = (const float*)d_in[4];
    const float* w3 = (const float*)d_in[5];
    const float* um = (const float*)d_in[6];
    const int steps = in_sizes[6] / (NB * NH * NW);

    const size_t npix  = (size_t)NB * NH * NW;
    const size_t nelem = (size_t)NB * NC * NH * NW;

    // ws: packed state (16 MB) + sidecars (2x1 MB) + preb (2x0.5 MB) + wf
    ushort_t* bfW        = (ushort_t*)d_ws;                 // 16 MB
    ushort_t* scA        = bfW + nelem;                     // 1 MB
    ushort_t* scB        = scA + npix;                      // 1 MB
    unsigned char* prebA = (unsigned char*)(scB + npix);    // 512 KB
    unsigned char* prebB = prebA + npix;                    // 512 KB
    int4* wf             = (int4*)(prebB + npix);           // 18 KB
    // second state buffer borrows d_out's first 16 MB (dead before final)
    ushort_t* bfO        = (ushort_t*)d_out;
    float* xout          = (float*)d_out;

    prep_weights<<<18, 64, 0, stream>>>(w1, b1, w2, w3, wf);

    dim3 grd(NH, NB);

    // ensure the LAST step writes to the ws buffer (bfW), since nca_final
    // reads it while writing d_out.
    auto stbuf = [&](int i) -> ushort_t* {
        return (((steps - 1 - i) & 1) == 0) ? bfW : bfO;
    };

    const ushort_t* cur_ps = nullptr;
    const ushort_t* cur_sc = nullptr;
    unsigned char* preb_last = prebA;

    for (int i = 0; i < steps; ++i) {
        const float* um_i = um + (size_t)i * npix;
        ushort_t* pso      = stbuf(i);
        ushort_t* sco      = (i % 2 == 0) ? scA : scB;
        unsigned char* po  = (i % 2 == 0) ? prebA : prebB;
        unsigned char* pin = (i % 2 == 0) ? prebB : prebA;

        if (i == 0)
            nca_first<<<grd, 256, 0, stream>>>(x, um_i, wf, b2, pso, sco, po);
        else
            nca_step<<<grd, 256, 0, stream>>>(cur_ps, cur_sc, pin, um_i, wf, b2,
                                              pso, sco, po);
        cur_ps = pso;
        cur_sc = sco;
        preb_last = po;
    }

    nca_final<<<grd, 256, 0, stream>>>(cur_ps, cur_sc, preb_last, xout);
}